// Round 3
// baseline (898.544 us; speedup 1.0000x reference)
//
#include <hip/hip_runtime.h>

// ConvLSTM2D x2 encoder — bf16 MFMA implicit-GEMM, round 3.
// Changes vs round 2:
//  - B (weights) pre-swizzled to MFMA fragment-linear order: each b[g] load is
//    base + lane*16B, one coalesced 1KB burst (was a 16-cacheline gather).
//  - L0(t) and L1(t-1) merged into one dispatch (independent work): 512 blocks
//    = 2 blocks/CU = 16 waves/CU (was 256 blocks = 8 waves/CU, latency-bound).
//  - __launch_bounds__(512,4) caps VGPR at 128 so 2 blocks/CU fit.

typedef __bf16 bf16x8 __attribute__((ext_vector_type(8)));
typedef float f32x4 __attribute__((ext_vector_type(4)));

#define BHWF (8 * 64 * 64 * 64)   // elems per [B,H,W,F] state tensor
#define TSTRIDE 72                // LDS tile channel stride (bf16 units)

__device__ __forceinline__ float hsig(float x) {
    return fminf(fmaxf(fmaf(0.2f, x, 0.5f), 0.0f), 1.0f);
}

__device__ __forceinline__ ushort f2bf(float f) {
    unsigned u = __float_as_uint(f);
    return (ushort)((u + 0x7FFFu + ((u >> 16) & 1u)) >> 16);
}

// Swizzle fp32 W[k=576][n=256] -> bf16 fragment-linear:
//   o = ((((tap*2+kc)*4 + fq)*4 + g)*64 + lane)*8 + e
//   n = g*64 + fq*16 + (lane&15); k = tap*64 + kc*32 + (lane>>4)*8 + e
// grid(576,3) x 256 — 147456 elems per tensor, exact.
__global__ void prep_w(const float* __restrict__ s0, const float* __restrict__ s1,
                       const float* __restrict__ s2,
                       ushort* __restrict__ d0, ushort* __restrict__ d1,
                       ushort* __restrict__ d2) {
    const float* s[3] = { s0, s1, s2 };
    ushort* d[3] = { d0, d1, d2 };
    int o = blockIdx.x * 256 + threadIdx.x;
    int e    = o & 7;
    int lane = (o >> 3) & 63;
    int g    = (o >> 9) & 3;
    int fq   = (o >> 11) & 3;
    int kc   = (o >> 13) & 1;
    int tap  = o >> 14;
    int n = g * 64 + fq * 16 + (lane & 15);
    int k = tap * 64 + kc * 32 + (lane >> 4) * 8 + e;
    d[blockIdx.y][o] = f2bf(s[blockIdx.y][k * 256 + n]);
}

// Stage 10x18 halo tile of bf16 [4096][64] image into LDS [cell][TSTRIDE].
__device__ __forceinline__ void stage(const ushort* __restrict__ src,
                                      ushort* __restrict__ tile,
                                      int y0, int x0, int tid) {
    for (int v = tid; v < 1440; v += 512) {
        int cell = v >> 3, j = v & 7;
        int r = cell / 18, cc = cell - r * 18;
        int y = y0 - 1 + r, xx = x0 - 1 + cc;
        uint4 dv = make_uint4(0u, 0u, 0u, 0u);
        if ((unsigned)y < 64u && (unsigned)xx < 64u)
            dv = ((const uint4*)src)[(size_t)((y << 6) + xx) * 8 + j];
        *(uint4*)&tile[cell * TSTRIDE + j * 8] = dv;
    }
}

// 3x3x64 conv as 18 fragment iterations; WS is fragment-linear (see prep_w).
__device__ __forceinline__ void conv_mfma(const ushort* __restrict__ tile,
                                          const ushort* __restrict__ WS,
                                          f32x4 (&acc)[4][4],
                                          int mh, int fq, int lane) {
    const int colA = lane & 15;
    const int quad = (lane >> 4) & 3;
    const ushort* wbase = WS + fq * 2048 + lane * 8;
    #pragma unroll
    for (int tap = 0; tap < 9; ++tap) {
        const int dy = tap / 3, dx = tap - dy * 3;
        #pragma unroll
        for (int kc = 0; kc < 2; ++kc) {
            const ushort* wp = wbase + (tap * 2 + kc) * 8192;
            bf16x8 a[4], bb[4];
            #pragma unroll
            for (int mt = 0; mt < 4; ++mt) {
                int cell = (mh * 4 + mt + dy) * 18 + (colA + dx);
                a[mt] = *(const bf16x8*)&tile[cell * TSTRIDE + kc * 32 + quad * 8];
            }
            #pragma unroll
            for (int g = 0; g < 4; ++g)
                bb[g] = *(const bf16x8*)&wp[g * 512];
            #pragma unroll
            for (int mt = 0; mt < 4; ++mt)
                #pragma unroll
                for (int g = 0; g < 4; ++g)
                    acc[mt][g] = __builtin_amdgcn_mfma_f32_16x16x32_bf16(
                        a[mt], bb[g], acc[mt][g], 0, 0, 0);
        }
    }
}

// Merged step: z<zsplit -> L0 at time t, else L1 at time t-1 (independent).
__global__ __launch_bounds__(512, 4) void step_merged(
    int l0_active, int l1_active, int last0, int last1,
    // L0
    const float* __restrict__ x, const float* __restrict__ Wx0,
    const ushort* __restrict__ Wh0S, const float* __restrict__ b0,
    const ushort* __restrict__ h0_prev, float* __restrict__ c0,
    ushort* __restrict__ h0_out, float* __restrict__ oh0, float* __restrict__ oc0,
    // L1
    const ushort* __restrict__ xin, const ushort* __restrict__ Wx1S,
    const ushort* __restrict__ Wh1S, const float* __restrict__ b1,
    const ushort* __restrict__ h1_prev, float* __restrict__ c1,
    ushort* __restrict__ h1_out, float* __restrict__ oh1, float* __restrict__ oc1)
{
    __shared__ __align__(16) ushort tile[180 * TSTRIDE];
    __shared__ float xtile[180];

    const int z = blockIdx.z;
    bool isL1; int b;
    if (l0_active && l1_active) { isL1 = (z >= 8); b = z & 7; }
    else                        { isL1 = (l1_active != 0); b = z; }

    const int tid = threadIdx.x;
    const int lane = tid & 63;
    const int w = tid >> 6;
    const int mh = w & 1;               // m half: rows 0-3 or 4-7
    const int fq = w >> 1;              // f quad: f base = fq*16
    const int colA = lane & 15;
    const int quad = (lane >> 4) & 3;
    const int x0 = blockIdx.x * 16, y0 = blockIdx.y * 8;
    const int f = fq * 16 + colA;

    const ushort* h_prev = isL1 ? h1_prev : h0_prev;
    const float*  bias   = isL1 ? b1 : b0;
    float*        cbuf   = isL1 ? c1 : c0;
    ushort*       hout   = isL1 ? h1_out : h0_out;
    float* hf = isL1 ? (last1 ? oh1 : nullptr) : (last0 ? oh0 : nullptr);
    float* cf = isL1 ? (last1 ? oc1 : nullptr) : (last0 ? oc0 : nullptr);

    // ---- init accumulators with bias ----
    f32x4 acc[4][4];
    #pragma unroll
    for (int g = 0; g < 4; ++g) {
        float bv = bias[g * 64 + f];
        #pragma unroll
        for (int mt = 0; mt < 4; ++mt) {
            acc[mt][g][0] = bv; acc[mt][g][1] = bv;
            acc[mt][g][2] = bv; acc[mt][g][3] = bv;
        }
    }

    if (!isL1) {
        // stage fp32 x tile (Cin=1) and h tile together
        const float* xs = x + (size_t)b * 40960;
        for (int v = tid; v < 180; v += 512) {
            int r = v / 18, cc = v - r * 18;
            int y = y0 - 1 + r, xx = x0 - 1 + cc;
            xtile[v] = ((unsigned)y < 64u && (unsigned)xx < 64u) ? xs[(y << 6) + xx] : 0.f;
        }
        if (h_prev) stage(h_prev + (size_t)b * 4096 * 64, tile, y0, x0, tid);
        __syncthreads();

        // scalar x-conv (Cin=1) into acc
        float wx[9][4];
        #pragma unroll
        for (int tap = 0; tap < 9; ++tap)
            #pragma unroll
            for (int g = 0; g < 4; ++g)
                wx[tap][g] = Wx0[tap * 256 + g * 64 + f];
        #pragma unroll
        for (int mt = 0; mt < 4; ++mt) {
            const int rr = mh * 4 + mt;
            #pragma unroll
            for (int reg = 0; reg < 4; ++reg) {
                const int cc = quad * 4 + reg;
                float s0 = 0.f, s1 = 0.f, s2 = 0.f, s3 = 0.f;
                #pragma unroll
                for (int tap = 0; tap < 9; ++tap) {
                    int dy = tap / 3, dx = tap - dy * 3;
                    float xv = xtile[(rr + dy) * 18 + cc + dx];
                    s0 = fmaf(xv, wx[tap][0], s0);
                    s1 = fmaf(xv, wx[tap][1], s1);
                    s2 = fmaf(xv, wx[tap][2], s2);
                    s3 = fmaf(xv, wx[tap][3], s3);
                }
                acc[mt][0][reg] += s0; acc[mt][1][reg] += s1;
                acc[mt][2][reg] += s2; acc[mt][3][reg] += s3;
            }
        }
        if (h_prev) conv_mfma(tile, Wh0S, acc, mh, fq, lane);
    } else {
        stage(xin + (size_t)b * 4096 * 64, tile, y0, x0, tid);
        __syncthreads();
        conv_mfma(tile, Wx1S, acc, mh, fq, lane);
        if (h_prev) {
            __syncthreads();
            stage(h_prev + (size_t)b * 4096 * 64, tile, y0, x0, tid);
            __syncthreads();
            conv_mfma(tile, Wh1S, acc, mh, fq, lane);
        }
    }

    // ---- LSTM pointwise epilogue ----
    #pragma unroll
    for (int mt = 0; mt < 4; ++mt) {
        const int y = y0 + mh * 4 + mt;
        #pragma unroll
        for (int reg = 0; reg < 4; ++reg) {
            const int xx = x0 + quad * 4 + reg;
            const size_t pidx = ((size_t)b * 4096 + (y << 6) + xx) * 64 + f;
            float cp = h_prev ? cbuf[pidx] : 0.f;
            float iv = hsig(acc[mt][0][reg]);
            float fv = hsig(acc[mt][1][reg]);
            float gv = tanhf(acc[mt][2][reg]);
            float ov = hsig(acc[mt][3][reg]);
            float cn = fmaf(fv, cp, iv * gv);
            float hn = ov * tanhf(cn);
            cbuf[pidx] = cn;
            hout[pidx] = f2bf(hn);
            if (hf) { hf[pidx] = hn; cf[pidx] = cn; }
        }
    }
}

extern "C" void kernel_launch(void* const* d_in, const int* in_sizes, int n_in,
                              void* d_out, int out_size, void* d_ws, size_t ws_size,
                              hipStream_t stream) {
    const float* x   = (const float*)d_in[0];   // [8,10,64,64,1]
    const float* Wx0 = (const float*)d_in[1];   // [9][256] fp32
    const float* Wh0 = (const float*)d_in[2];   // [576][256] fp32
    const float* b0  = (const float*)d_in[3];
    const float* Wx1 = (const float*)d_in[4];
    const float* Wh1 = (const float*)d_in[5];
    const float* b1  = (const float*)d_in[6];
    float* out = (float*)d_out;                 // [2,2,8,64,64,64] fp32
    char* ws = (char*)d_ws;

    ushort* h0buf[2] = { (ushort*)ws, (ushort*)(ws + 4u * 1024 * 1024) };
    ushort* h1buf[2] = { (ushort*)(ws + 8u * 1024 * 1024), (ushort*)(ws + 12u * 1024 * 1024) };
    float* c0 = (float*)(ws + 16u * 1024 * 1024);
    float* c1 = (float*)(ws + 24u * 1024 * 1024);
    ushort* Wh0S = (ushort*)(ws + 32u * 1024 * 1024);
    ushort* Wx1S = Wh0S + 147456;
    ushort* Wh1S = Wx1S + 147456;

    prep_w<<<dim3(576, 3), 256, 0, stream>>>(Wh0, Wx1, Wh1, Wh0S, Wx1S, Wh1S);

    for (int t = 0; t <= 10; ++t) {
        const int has0 = (t < 10), has1 = (t >= 1);
        const int s = t - 1;                    // L1 time index
        const int tx = has0 ? t : 9;            // clamp pointer math
        dim3 grid(4, 8, (has0 && has1) ? 16 : 8);
        step_merged<<<grid, 512, 0, stream>>>(
            has0, has1, (t == 9), (s == 9),
            x + (size_t)tx * 4096, Wx0,
            (t >= 1) ? Wh0S : nullptr, b0,
            (t >= 1 && has0) ? h0buf[(t - 1) & 1] : nullptr, c0,
            h0buf[t & 1], out, out + BHWF,
            has1 ? h0buf[s & 1] : nullptr, Wx1S,
            Wh1S, b1,
            (s >= 1) ? h1buf[(s - 1) & 1] : nullptr, c1,
            h1buf[s & 1], out + 2 * (size_t)BHWF, out + 3 * (size_t)BHWF);
    }
}

// Round 4
// 510.809 us; speedup vs baseline: 1.7591x; 1.7591x over previous
//
#include <hip/hip_runtime.h>

// ConvLSTM2D x2 encoder — bf16 MFMA implicit-GEMM, round 4.
// Round 3's __launch_bounds__(512,4) caused scratch spill (VGPR 120->64,
// 155 MB/dispatch spill writes). Revert to (512,2): 120 VGPRs fits 4 waves/SIMD
// anyway (480<=512), so the 512-block merged grid still gets 2 blocks/CU.

typedef __bf16 bf16x8 __attribute__((ext_vector_type(8)));
typedef float f32x4 __attribute__((ext_vector_type(4)));

#define BHWF (8 * 64 * 64 * 64)   // elems per [B,H,W,F] state tensor
#define TSTRIDE 72                // LDS tile channel stride (bf16 units)

__device__ __forceinline__ float hsig(float x) {
    return fminf(fmaxf(fmaf(0.2f, x, 0.5f), 0.0f), 1.0f);
}

__device__ __forceinline__ ushort f2bf(float f) {
    unsigned u = __float_as_uint(f);
    return (ushort)((u + 0x7FFFu + ((u >> 16) & 1u)) >> 16);
}

// Swizzle fp32 W[k=576][n=256] -> bf16 fragment-linear:
//   o = ((((tap*2+kc)*4 + fq)*4 + g)*64 + lane)*8 + e
//   n = g*64 + fq*16 + (lane&15); k = tap*64 + kc*32 + (lane>>4)*8 + e
__global__ void prep_w(const float* __restrict__ s0, const float* __restrict__ s1,
                       const float* __restrict__ s2,
                       ushort* __restrict__ d0, ushort* __restrict__ d1,
                       ushort* __restrict__ d2) {
    const float* s[3] = { s0, s1, s2 };
    ushort* d[3] = { d0, d1, d2 };
    int o = blockIdx.x * 256 + threadIdx.x;
    int e    = o & 7;
    int lane = (o >> 3) & 63;
    int g    = (o >> 9) & 3;
    int fq   = (o >> 11) & 3;
    int kc   = (o >> 13) & 1;
    int tap  = o >> 14;
    int n = g * 64 + fq * 16 + (lane & 15);
    int k = tap * 64 + kc * 32 + (lane >> 4) * 8 + e;
    d[blockIdx.y][o] = f2bf(s[blockIdx.y][k * 256 + n]);
}

// Stage 10x18 halo tile of bf16 [4096][64] image into LDS [cell][TSTRIDE].
__device__ __forceinline__ void stage(const ushort* __restrict__ src,
                                      ushort* __restrict__ tile,
                                      int y0, int x0, int tid) {
    for (int v = tid; v < 1440; v += 512) {
        int cell = v >> 3, j = v & 7;
        int r = cell / 18, cc = cell - r * 18;
        int y = y0 - 1 + r, xx = x0 - 1 + cc;
        uint4 dv = make_uint4(0u, 0u, 0u, 0u);
        if ((unsigned)y < 64u && (unsigned)xx < 64u)
            dv = ((const uint4*)src)[(size_t)((y << 6) + xx) * 8 + j];
        *(uint4*)&tile[cell * TSTRIDE + j * 8] = dv;
    }
}

// 3x3x64 conv as 18 fragment iterations; WS is fragment-linear (see prep_w).
__device__ __forceinline__ void conv_mfma(const ushort* __restrict__ tile,
                                          const ushort* __restrict__ WS,
                                          f32x4 (&acc)[4][4],
                                          int mh, int fq, int lane) {
    const int colA = lane & 15;
    const int quad = (lane >> 4) & 3;
    const ushort* wbase = WS + fq * 2048 + lane * 8;
    #pragma unroll
    for (int tap = 0; tap < 9; ++tap) {
        const int dy = tap / 3, dx = tap - dy * 3;
        #pragma unroll
        for (int kc = 0; kc < 2; ++kc) {
            const ushort* wp = wbase + (tap * 2 + kc) * 8192;
            bf16x8 a[4], bb[4];
            #pragma unroll
            for (int mt = 0; mt < 4; ++mt) {
                int cell = (mh * 4 + mt + dy) * 18 + (colA + dx);
                a[mt] = *(const bf16x8*)&tile[cell * TSTRIDE + kc * 32 + quad * 8];
            }
            #pragma unroll
            for (int g = 0; g < 4; ++g)
                bb[g] = *(const bf16x8*)&wp[g * 512];
            #pragma unroll
            for (int mt = 0; mt < 4; ++mt)
                #pragma unroll
                for (int g = 0; g < 4; ++g)
                    acc[mt][g] = __builtin_amdgcn_mfma_f32_16x16x32_bf16(
                        a[mt], bb[g], acc[mt][g], 0, 0, 0);
        }
    }
}

// Merged step: z<8 -> L0 at time t, z>=8 -> L1 at time t-1 (independent work).
__global__ __launch_bounds__(512, 2) void step_merged(
    int l0_active, int l1_active, int last0, int last1,
    // L0
    const float* __restrict__ x, const float* __restrict__ Wx0,
    const ushort* __restrict__ Wh0S, const float* __restrict__ b0,
    const ushort* __restrict__ h0_prev, float* __restrict__ c0,
    ushort* __restrict__ h0_out, float* __restrict__ oh0, float* __restrict__ oc0,
    // L1
    const ushort* __restrict__ xin, const ushort* __restrict__ Wx1S,
    const ushort* __restrict__ Wh1S, const float* __restrict__ b1,
    const ushort* __restrict__ h1_prev, float* __restrict__ c1,
    ushort* __restrict__ h1_out, float* __restrict__ oh1, float* __restrict__ oc1)
{
    __shared__ __align__(16) ushort tile[180 * TSTRIDE];
    __shared__ float xtile[180];

    const int z = blockIdx.z;
    bool isL1; int b;
    if (l0_active && l1_active) { isL1 = (z >= 8); b = z & 7; }
    else                        { isL1 = (l1_active != 0); b = z; }

    const int tid = threadIdx.x;
    const int lane = tid & 63;
    const int w = tid >> 6;
    const int mh = w & 1;               // m half: rows 0-3 or 4-7
    const int fq = w >> 1;              // f quad: f base = fq*16
    const int colA = lane & 15;
    const int quad = (lane >> 4) & 3;
    const int x0 = blockIdx.x * 16, y0 = blockIdx.y * 8;
    const int f = fq * 16 + colA;

    const ushort* h_prev = isL1 ? h1_prev : h0_prev;
    const float*  bias   = isL1 ? b1 : b0;
    float*        cbuf   = isL1 ? c1 : c0;
    ushort*       hout   = isL1 ? h1_out : h0_out;
    float* hf = isL1 ? (last1 ? oh1 : nullptr) : (last0 ? oh0 : nullptr);
    float* cf = isL1 ? (last1 ? oc1 : nullptr) : (last0 ? oc0 : nullptr);

    // ---- init accumulators with bias ----
    f32x4 acc[4][4];
    #pragma unroll
    for (int g = 0; g < 4; ++g) {
        float bv = bias[g * 64 + f];
        #pragma unroll
        for (int mt = 0; mt < 4; ++mt) {
            acc[mt][g][0] = bv; acc[mt][g][1] = bv;
            acc[mt][g][2] = bv; acc[mt][g][3] = bv;
        }
    }

    if (!isL1) {
        // stage fp32 x tile (Cin=1) and h tile together
        const float* xs = x + (size_t)b * 40960;
        for (int v = tid; v < 180; v += 512) {
            int r = v / 18, cc = v - r * 18;
            int y = y0 - 1 + r, xx = x0 - 1 + cc;
            xtile[v] = ((unsigned)y < 64u && (unsigned)xx < 64u) ? xs[(y << 6) + xx] : 0.f;
        }
        if (h_prev) stage(h_prev + (size_t)b * 4096 * 64, tile, y0, x0, tid);
        __syncthreads();

        // scalar x-conv (Cin=1) into acc
        float wx[9][4];
        #pragma unroll
        for (int tap = 0; tap < 9; ++tap)
            #pragma unroll
            for (int g = 0; g < 4; ++g)
                wx[tap][g] = Wx0[tap * 256 + g * 64 + f];
        #pragma unroll
        for (int mt = 0; mt < 4; ++mt) {
            const int rr = mh * 4 + mt;
            #pragma unroll
            for (int reg = 0; reg < 4; ++reg) {
                const int cc = quad * 4 + reg;
                float s0 = 0.f, s1 = 0.f, s2 = 0.f, s3 = 0.f;
                #pragma unroll
                for (int tap = 0; tap < 9; ++tap) {
                    int dy = tap / 3, dx = tap - dy * 3;
                    float xv = xtile[(rr + dy) * 18 + cc + dx];
                    s0 = fmaf(xv, wx[tap][0], s0);
                    s1 = fmaf(xv, wx[tap][1], s1);
                    s2 = fmaf(xv, wx[tap][2], s2);
                    s3 = fmaf(xv, wx[tap][3], s3);
                }
                acc[mt][0][reg] += s0; acc[mt][1][reg] += s1;
                acc[mt][2][reg] += s2; acc[mt][3][reg] += s3;
            }
        }
        if (h_prev) conv_mfma(tile, Wh0S, acc, mh, fq, lane);
    } else {
        stage(xin + (size_t)b * 4096 * 64, tile, y0, x0, tid);
        __syncthreads();
        conv_mfma(tile, Wx1S, acc, mh, fq, lane);
        if (h_prev) {
            __syncthreads();
            stage(h_prev + (size_t)b * 4096 * 64, tile, y0, x0, tid);
            __syncthreads();
            conv_mfma(tile, Wh1S, acc, mh, fq, lane);
        }
    }

    // ---- LSTM pointwise epilogue ----
    #pragma unroll
    for (int mt = 0; mt < 4; ++mt) {
        const int y = y0 + mh * 4 + mt;
        #pragma unroll
        for (int reg = 0; reg < 4; ++reg) {
            const int xx = x0 + quad * 4 + reg;
            const size_t pidx = ((size_t)b * 4096 + (y << 6) + xx) * 64 + f;
            float cp = h_prev ? cbuf[pidx] : 0.f;
            float iv = hsig(acc[mt][0][reg]);
            float fv = hsig(acc[mt][1][reg]);
            float gv = tanhf(acc[mt][2][reg]);
            float ov = hsig(acc[mt][3][reg]);
            float cn = fmaf(fv, cp, iv * gv);
            float hn = ov * tanhf(cn);
            cbuf[pidx] = cn;
            hout[pidx] = f2bf(hn);
            if (hf) { hf[pidx] = hn; cf[pidx] = cn; }
        }
    }
}

extern "C" void kernel_launch(void* const* d_in, const int* in_sizes, int n_in,
                              void* d_out, int out_size, void* d_ws, size_t ws_size,
                              hipStream_t stream) {
    const float* x   = (const float*)d_in[0];   // [8,10,64,64,1]
    const float* Wx0 = (const float*)d_in[1];   // [9][256] fp32
    const float* Wh0 = (const float*)d_in[2];   // [576][256] fp32
    const float* b0  = (const float*)d_in[3];
    const float* Wx1 = (const float*)d_in[4];
    const float* Wh1 = (const float*)d_in[5];
    const float* b1  = (const float*)d_in[6];
    float* out = (float*)d_out;                 // [2,2,8,64,64,64] fp32
    char* ws = (char*)d_ws;

    ushort* h0buf[2] = { (ushort*)ws, (ushort*)(ws + 4u * 1024 * 1024) };
    ushort* h1buf[2] = { (ushort*)(ws + 8u * 1024 * 1024), (ushort*)(ws + 12u * 1024 * 1024) };
    float* c0 = (float*)(ws + 16u * 1024 * 1024);
    float* c1 = (float*)(ws + 24u * 1024 * 1024);
    ushort* Wh0S = (ushort*)(ws + 32u * 1024 * 1024);
    ushort* Wx1S = Wh0S + 147456;
    ushort* Wh1S = Wx1S + 147456;

    prep_w<<<dim3(576, 3), 256, 0, stream>>>(Wh0, Wx1, Wh1, Wh0S, Wx1S, Wh1S);

    for (int t = 0; t <= 10; ++t) {
        const int has0 = (t < 10), has1 = (t >= 1);
        const int s = t - 1;                    // L1 time index
        const int tx = has0 ? t : 9;            // clamp pointer math
        dim3 grid(4, 8, (has0 && has1) ? 16 : 8);
        step_merged<<<grid, 512, 0, stream>>>(
            has0, has1, (t == 9), (s == 9),
            x + (size_t)tx * 4096, Wx0,
            (t >= 1) ? Wh0S : nullptr, b0,
            (t >= 1 && has0) ? h0buf[(t - 1) & 1] : nullptr, c0,
            h0buf[t & 1], out, out + BHWF,
            has1 ? h0buf[s & 1] : nullptr, Wx1S,
            Wh1S, b1,
            (s >= 1) ? h1buf[(s - 1) & 1] : nullptr, c1,
            h1buf[s & 1], out + 2 * (size_t)BHWF, out + 3 * (size_t)BHWF);
    }
}

// Round 5
// 483.168 us; speedup vs baseline: 1.8597x; 1.0572x over previous
//
#include <hip/hip_runtime.h>

// ConvLSTM2D x2 encoder — bf16 MFMA implicit-GEMM, round 5.
// Round-4 model: LDS-read-bound (72 ds_read_b128 per wave-conv vs 288 MFMA
// -> 27% ceiling, measured 21%). Changes:
//  - A-fragment ring: kc->dy->dx loop, Ar[6][3] register ring, each (row,dx)
//    fragment read once per kc -> 36 reads/wave-conv (2x LDS cut).
//  - 4-wave blocks (256 thr), tile 16x4, grid(4,16,16)=1024 blocks ->
//    3 blocks/CU = 12 waves/CU (was 8).
//  - L1 stages both tiles, one barrier, two back-to-back convs.

typedef __bf16 bf16x8 __attribute__((ext_vector_type(8)));
typedef float f32x4 __attribute__((ext_vector_type(4)));

#define BHWF (8 * 64 * 64 * 64)
#define TSTRIDE 72                // LDS cell stride (bf16 units)
#define NCELL 108                 // 6 rows x 18 cols halo tile

__device__ __forceinline__ float hsig(float x) {
    return fminf(fmaxf(fmaf(0.2f, x, 0.5f), 0.0f), 1.0f);
}

__device__ __forceinline__ ushort f2bf(float f) {
    unsigned u = __float_as_uint(f);
    return (ushort)((u + 0x7FFFu + ((u >> 16) & 1u)) >> 16);
}

// Swizzle fp32 W[k=576][n=256] -> bf16 fragment-linear (same as round 4).
__global__ void prep_w(const float* __restrict__ s0, const float* __restrict__ s1,
                       const float* __restrict__ s2,
                       ushort* __restrict__ d0, ushort* __restrict__ d1,
                       ushort* __restrict__ d2) {
    const float* s[3] = { s0, s1, s2 };
    ushort* d[3] = { d0, d1, d2 };
    int o = blockIdx.x * 256 + threadIdx.x;
    int e    = o & 7;
    int lane = (o >> 3) & 63;
    int g    = (o >> 9) & 3;
    int fq   = (o >> 11) & 3;
    int kc   = (o >> 13) & 1;
    int tap  = o >> 14;
    int n = g * 64 + fq * 16 + (lane & 15);
    int k = tap * 64 + kc * 32 + (lane >> 4) * 8 + e;
    d[blockIdx.y][o] = f2bf(s[blockIdx.y][k * 256 + n]);
}

// Stage 6x18 halo tile of bf16 [4096][64] image into LDS [cell][TSTRIDE].
__device__ __forceinline__ void stage(const ushort* __restrict__ src,
                                      ushort* __restrict__ tile,
                                      int y0, int x0, int tid) {
    for (int v = tid; v < NCELL * 8; v += 256) {
        int cell = v >> 3, j = v & 7;
        int r = cell / 18, cc = cell - r * 18;
        int y = y0 - 1 + r, xx = x0 - 1 + cc;
        uint4 dv = make_uint4(0u, 0u, 0u, 0u);
        if ((unsigned)y < 64u && (unsigned)xx < 64u)
            dv = ((const uint4*)src)[(size_t)((y << 6) + xx) * 8 + j];
        *(uint4*)&tile[cell * TSTRIDE + j * 8] = dv;
    }
}

// 3x3x64 conv; A-fragment register ring (each (row,dx) read once per kc).
__device__ __forceinline__ void conv_ring(const ushort* __restrict__ tile,
                                          const ushort* __restrict__ WS,
                                          f32x4 (&acc)[4][4],
                                          int fq, int lane) {
    const int colA = lane & 15;
    const int quad = (lane >> 4) & 3;
    const ushort* wbase = WS + fq * 2048 + lane * 8;
    #pragma unroll
    for (int kc = 0; kc < 2; ++kc) {
        bf16x8 Ar[6][3];
        #pragma unroll
        for (int dy = 0; dy < 3; ++dy) {
            #pragma unroll
            for (int dx = 0; dx < 3; ++dx) {
                const int tap = dy * 3 + dx;
                const ushort* wp = wbase + (tap * 2 + kc) * 8192;
                bf16x8 b0 = *(const bf16x8*)&wp[0];
                bf16x8 b1 = *(const bf16x8*)&wp[512];
                bf16x8 b2 = *(const bf16x8*)&wp[1024];
                bf16x8 b3 = *(const bf16x8*)&wp[1536];
                #pragma unroll
                for (int mt = 0; mt < 4; ++mt) {
                    const int r = mt + dy;
                    if (dy == 0 || mt == 3)   // first use of (r,dx) this kc
                        Ar[r][dx] = *(const bf16x8*)&tile[
                            (r * 18 + colA + dx) * TSTRIDE + kc * 32 + quad * 8];
                    acc[mt][0] = __builtin_amdgcn_mfma_f32_16x16x32_bf16(Ar[r][dx], b0, acc[mt][0], 0, 0, 0);
                    acc[mt][1] = __builtin_amdgcn_mfma_f32_16x16x32_bf16(Ar[r][dx], b1, acc[mt][1], 0, 0, 0);
                    acc[mt][2] = __builtin_amdgcn_mfma_f32_16x16x32_bf16(Ar[r][dx], b2, acc[mt][2], 0, 0, 0);
                    acc[mt][3] = __builtin_amdgcn_mfma_f32_16x16x32_bf16(Ar[r][dx], b3, acc[mt][3], 0, 0, 0);
                }
            }
        }
    }
}

// Merged step: z<8 -> L0 at time t, z>=8 -> L1 at time t-1 (independent work).
__global__ __launch_bounds__(256, 3) void step_merged(
    int l0_active, int l1_active, int last0, int last1,
    const float* __restrict__ x, const float* __restrict__ Wx0,
    const ushort* __restrict__ Wh0S, const float* __restrict__ b0,
    const ushort* __restrict__ h0_prev, float* __restrict__ c0,
    ushort* __restrict__ h0_out, float* __restrict__ oh0, float* __restrict__ oc0,
    const ushort* __restrict__ xin, const ushort* __restrict__ Wx1S,
    const ushort* __restrict__ Wh1S, const float* __restrict__ b1,
    const ushort* __restrict__ h1_prev, float* __restrict__ c1,
    ushort* __restrict__ h1_out, float* __restrict__ oh1, float* __restrict__ oc1)
{
    __shared__ __align__(16) ushort tile1[NCELL * TSTRIDE];
    __shared__ __align__(16) ushort tile2[NCELL * TSTRIDE];
    __shared__ float xtile[NCELL];

    const int z = blockIdx.z;
    bool isL1; int b;
    if (l0_active && l1_active) { isL1 = (z >= 8); b = z & 7; }
    else                        { isL1 = (l1_active != 0); b = z; }

    const int tid = threadIdx.x;
    const int lane = tid & 63;
    const int fq = tid >> 6;            // wave id = f quad
    const int colA = lane & 15;
    const int quad = (lane >> 4) & 3;
    const int x0 = blockIdx.x * 16, y0 = blockIdx.y * 4;
    const int f = fq * 16 + colA;

    const ushort* h_prev = isL1 ? h1_prev : h0_prev;
    const float*  bias   = isL1 ? b1 : b0;
    float*        cbuf   = isL1 ? c1 : c0;
    ushort*       hout   = isL1 ? h1_out : h0_out;
    float* hf = isL1 ? (last1 ? oh1 : nullptr) : (last0 ? oh0 : nullptr);
    float* cf = isL1 ? (last1 ? oc1 : nullptr) : (last0 ? oc0 : nullptr);

    // ---- stage ----
    if (!isL1) {
        const float* xs = x + (size_t)b * 40960;
        for (int v = tid; v < NCELL; v += 256) {
            int r = v / 18, cc = v - r * 18;
            int y = y0 - 1 + r, xx = x0 - 1 + cc;
            xtile[v] = ((unsigned)y < 64u && (unsigned)xx < 64u) ? xs[(y << 6) + xx] : 0.f;
        }
        if (h_prev) stage(h_prev + (size_t)b * 4096 * 64, tile1, y0, x0, tid);
    } else {
        stage(xin + (size_t)b * 4096 * 64, tile1, y0, x0, tid);
        if (h_prev) stage(h_prev + (size_t)b * 4096 * 64, tile2, y0, x0, tid);
    }
    __syncthreads();

    // ---- init accumulators with bias ----
    f32x4 acc[4][4];
    #pragma unroll
    for (int g = 0; g < 4; ++g) {
        float bv = bias[g * 64 + f];
        #pragma unroll
        for (int mt = 0; mt < 4; ++mt) {
            acc[mt][g][0] = bv; acc[mt][g][1] = bv;
            acc[mt][g][2] = bv; acc[mt][g][3] = bv;
        }
    }

    if (!isL1) {
        // scalar x-conv (Cin=1)
        float wx[9][4];
        #pragma unroll
        for (int tap = 0; tap < 9; ++tap)
            #pragma unroll
            for (int g = 0; g < 4; ++g)
                wx[tap][g] = Wx0[tap * 256 + g * 64 + f];
        #pragma unroll
        for (int mt = 0; mt < 4; ++mt) {
            #pragma unroll
            for (int reg = 0; reg < 4; ++reg) {
                const int cc = quad * 4 + reg;
                float s0 = 0.f, s1 = 0.f, s2 = 0.f, s3 = 0.f;
                #pragma unroll
                for (int tap = 0; tap < 9; ++tap) {
                    int dy = tap / 3, dx = tap - dy * 3;
                    float xv = xtile[(mt + dy) * 18 + cc + dx];
                    s0 = fmaf(xv, wx[tap][0], s0);
                    s1 = fmaf(xv, wx[tap][1], s1);
                    s2 = fmaf(xv, wx[tap][2], s2);
                    s3 = fmaf(xv, wx[tap][3], s3);
                }
                acc[mt][0][reg] += s0; acc[mt][1][reg] += s1;
                acc[mt][2][reg] += s2; acc[mt][3][reg] += s3;
            }
        }
        if (h_prev) conv_ring(tile1, Wh0S, acc, fq, lane);
    } else {
        conv_ring(tile1, Wx1S, acc, fq, lane);
        if (h_prev) conv_ring(tile2, Wh1S, acc, fq, lane);
    }

    // ---- LSTM pointwise epilogue ----
    #pragma unroll
    for (int mt = 0; mt < 4; ++mt) {
        const int y = y0 + mt;
        #pragma unroll
        for (int reg = 0; reg < 4; ++reg) {
            const int xx = x0 + quad * 4 + reg;
            const size_t pidx = ((size_t)b * 4096 + (y << 6) + xx) * 64 + f;
            float cp = h_prev ? cbuf[pidx] : 0.f;
            float iv = hsig(acc[mt][0][reg]);
            float fv = hsig(acc[mt][1][reg]);
            float gv = tanhf(acc[mt][2][reg]);
            float ov = hsig(acc[mt][3][reg]);
            float cn = fmaf(fv, cp, iv * gv);
            float hn = ov * tanhf(cn);
            cbuf[pidx] = cn;
            hout[pidx] = f2bf(hn);
            if (hf) { hf[pidx] = hn; cf[pidx] = cn; }
        }
    }
}

extern "C" void kernel_launch(void* const* d_in, const int* in_sizes, int n_in,
                              void* d_out, int out_size, void* d_ws, size_t ws_size,
                              hipStream_t stream) {
    const float* x   = (const float*)d_in[0];
    const float* Wx0 = (const float*)d_in[1];
    const float* Wh0 = (const float*)d_in[2];
    const float* b0  = (const float*)d_in[3];
    const float* Wx1 = (const float*)d_in[4];
    const float* Wh1 = (const float*)d_in[5];
    const float* b1  = (const float*)d_in[6];
    float* out = (float*)d_out;
    char* ws = (char*)d_ws;

    ushort* h0buf[2] = { (ushort*)ws, (ushort*)(ws + 4u * 1024 * 1024) };
    ushort* h1buf[2] = { (ushort*)(ws + 8u * 1024 * 1024), (ushort*)(ws + 12u * 1024 * 1024) };
    float* c0 = (float*)(ws + 16u * 1024 * 1024);
    float* c1 = (float*)(ws + 24u * 1024 * 1024);
    ushort* Wh0S = (ushort*)(ws + 32u * 1024 * 1024);
    ushort* Wx1S = Wh0S + 147456;
    ushort* Wh1S = Wx1S + 147456;

    prep_w<<<dim3(576, 3), 256, 0, stream>>>(Wh0, Wx1, Wh1, Wh0S, Wx1S, Wh1S);

    for (int t = 0; t <= 10; ++t) {
        const int has0 = (t < 10), has1 = (t >= 1);
        const int s = t - 1;
        const int tx = has0 ? t : 9;
        dim3 grid(4, 16, (has0 && has1) ? 16 : 8);
        step_merged<<<grid, 256, 0, stream>>>(
            has0, has1, (t == 9), (s == 9),
            x + (size_t)tx * 4096, Wx0,
            (t >= 1) ? Wh0S : nullptr, b0,
            (t >= 1 && has0) ? h0buf[(t - 1) & 1] : nullptr, c0,
            h0buf[t & 1], out, out + BHWF,
            has1 ? h0buf[s & 1] : nullptr, Wx1S,
            Wh1S, b1,
            (s >= 1) ? h1buf[(s - 1) & 1] : nullptr, c1,
            h1buf[s & 1], out + 2 * (size_t)BHWF, out + 3 * (size_t)BHWF);
    }
}